// Round 9
// baseline (249.158 us; speedup 1.0000x reference)
//
#include <hip/hip_runtime.h>

// SSIM over (32,3,512,512) fp32 pairs, 11x11 gaussian sigma=1.5, VALID conv,
// scalar mean output. Fused separable conv, 4 v-stat channels (x, y, x2+y2,
// x*y) staged in LDS (XOR-swizzled), horizontal 11-tap conv + SSIM + mean.
//
// R6: cohort fit. Residency = 4 blocks/CU (LDS 34.8KB) => 1024 co-resident.
// R4/R5's grid of 1056 = 1024 + 32 ran a SECOND round for the 32 stragglers
// at 3% utilization — half the dispatch was tail (fits R0-R5: dur = T_b x
// rounds). Grid 10x96 = 960 <= 1024 -> single cohort. RPB 52 (13 iters,
// +8%/block). Everything else identical to R5 for clean attribution.

namespace {
constexpr int IMG_H = 512;
constexpr int IMG_W = 512;
constexpr int NIMG  = 96;            // B*C = 32*3
constexpr int OUT_H = 502;
constexpr int OUT_W = 502;
constexpr int RPB   = 52;            // output rows per block (10 x-blocks = 960 total)
constexpr int QR    = 4;             // output rows per inner iteration
constexpr int WIN   = QR + 10;       // rolling window rows
constexpr int BUFW  = 544;           // 136 col4 slots * 4 floats (512 data + halo/pad)
constexpr double TOTAL = 24192384.0; // 96*502*502

// exp(-k^2/4.5) for k=5..1, normalized at compile time
constexpr double U0 = 0.0038659201;
constexpr double U1 = 0.0285655007;
constexpr double U2 = 0.1353352832366127;
constexpr double U3 = 0.4111122898;
constexpr double U4 = 0.8007374026;
constexpr double S  = 1.0 + 2.0 * (U0 + U1 + U2 + U3 + U4);
}

typedef float vf2 __attribute__((ext_vector_type(2)));

__device__ __forceinline__ vf2 pk_fma(float w, vf2 a, vf2 c) {
    vf2 wv = {w, w};
    return __builtin_elementwise_fma(wv, a, c);   // -> v_pk_fma_f32
}

__global__ __launch_bounds__(256, 2) void ssim_main(const float* __restrict__ img1,
                                                    const float* __restrict__ img2,
                                                    double* __restrict__ acc)
{
    __shared__ __align__(16) float vrow[QR][4][BUFW];   // 34816 B
    __shared__ float red[4];

    const float g[11] = {
        (float)(U0/S), (float)(U1/S), (float)(U2/S), (float)(U3/S), (float)(U4/S),
        (float)(1.0/S),
        (float)(U4/S), (float)(U3/S), (float)(U2/S), (float)(U1/S), (float)(U0/S)
    };
    constexpr float C1 = 1e-4f;   // 0.01^2
    constexpr float C2 = 9e-4f;   // 0.03^2

    const int t   = threadIdx.x;
    const int z   = blockIdx.y;
    const int oy0 = blockIdx.x * RPB;
    const int row_end = min(oy0 + RPB, OUT_H);

    const vf2* p1 = (const vf2*)(img1 + (size_t)z * (IMG_H * IMG_W)) + t;
    const vf2* p2 = (const vf2*)(img2 + (size_t)z * (IMG_H * IMG_W)) + t;

    // phase-V: thread owns input cols 2t, 2t+1. Swizzled write offset.
    const int c4w  = t >> 1;
    const int woff = ((c4w ^ ((c4w >> 3) & 7)) << 2) + ((t & 1) << 1);

    // phase-H: thread = (row hq 0..3, 8-col group at cb). Swizzled read offsets.
    const int hq = t >> 6;            // 0..3, all 256 threads active
    const int cb = (t & 63) << 3;     // 0..504
    int roff[5];
    #pragma unroll
    for (int k = 0; k < 5; ++k) {
        int c4 = (cb >> 2) + k;       // <= 130 < 136 slots
        roff[k] = (c4 ^ ((c4 >> 3) & 7)) << 2;
    }

    // rolling window: rows r0 .. r0+9 live at loop top
    vf2 wx[WIN], wy[WIN];
    #pragma unroll
    for (int j = 0; j < WIN - QR; ++j) {
        wx[j] = p1[(oy0 + j) * (IMG_W / 2)];
        wy[j] = p2[(oy0 + j) * (IMG_W / 2)];
    }

    float local = 0.f;

    for (int r0 = oy0; r0 < row_end; r0 += QR) {
        // ---- load the 4 new window rows (issued early, overlap with conv) ----
        #pragma unroll
        for (int i = 0; i < QR; ++i) {
            const int row = min(r0 + (WIN - QR) + i, IMG_H - 1);  // clamp: tail only
            wx[WIN - QR + i] = p1[row * (IMG_W / 2)];
            wy[WIN - QR + i] = p2[row * (IMG_W / 2)];
        }

        // ---- phase V: vertical 11-tap conv over the window, 4 channels, packed ----
        vf2 am1[QR], am2[QR], app[QR], axy[QR];
        #pragma unroll
        for (int q = 0; q < QR; ++q) {
            am1[q] = (vf2){0.f, 0.f};
            am2[q] = (vf2){0.f, 0.f};
            app[q] = (vf2){0.f, 0.f};
            axy[q] = (vf2){0.f, 0.f};
        }
        #pragma unroll
        for (int j = 0; j < WIN; ++j) {
            const vf2 x = wx[j], y = wy[j];
            const vf2 pp = __builtin_elementwise_fma(y, y, x * x);  // x^2 + y^2
            const vf2 xy = x * y;
            #pragma unroll
            for (int q = 0; q < QR; ++q) {
                const int k = j - q;
                if (k >= 0 && k < 11) {
                    const float w = g[k];
                    am1[q] = pk_fma(w, x,  am1[q]);
                    am2[q] = pk_fma(w, y,  am2[q]);
                    app[q] = pk_fma(w, pp, app[q]);
                    axy[q] = pk_fma(w, xy, axy[q]);
                }
            }
        }
        __syncthreads();   // previous iteration's phase-H reads complete
        #pragma unroll
        for (int q = 0; q < QR; ++q) {
            *(vf2*)&vrow[q][0][woff] = am1[q];
            *(vf2*)&vrow[q][1][woff] = am2[q];
            *(vf2*)&vrow[q][2][woff] = app[q];
            *(vf2*)&vrow[q][3][woff] = axy[q];
        }
        __syncthreads();   // v-stats visible

        // ---- shift window now: old rows die before phase-H's register peak ----
        #pragma unroll
        for (int j = 0; j < WIN - QR; ++j) { wx[j] = wx[j + QR]; wy[j] = wy[j + QR]; }

        // ---- phase H: horizontal 11-tap conv + SSIM, 8 cols/thread ----
        const int rr = r0 + hq;
        if (rr < row_end) {
            float aa[4][8];
            #pragma unroll
            for (int ch = 0; ch < 4; ++ch) {
                const float* bc = &vrow[hq][ch][0];
                float f[20];
                #pragma unroll
                for (int k = 0; k < 5; ++k) {
                    float4 v = *(const float4*)(bc + roff[k]);
                    f[4*k+0] = v.x; f[4*k+1] = v.y; f[4*k+2] = v.z; f[4*k+3] = v.w;
                }
                #pragma unroll
                for (int j = 0; j < 8; ++j) {
                    float s = 0.f;
                    #pragma unroll
                    for (int k = 0; k < 11; ++k) s = fmaf(g[k], f[j + k], s);
                    aa[ch][j] = s;
                }
            }
            #pragma unroll
            for (int j = 0; j < 8; ++j) {
                if (cb + j < OUT_W) {
                    float mu1 = aa[0][j], mu2 = aa[1][j];
                    float ee  = aa[2][j], e12 = aa[3][j];
                    float mu11 = mu1 * mu1;
                    float mu22 = mu2 * mu2;
                    float mu12 = mu1 * mu2;
                    float mm   = mu11 + mu22;
                    float s12  = e12 - mu12;
                    float spp  = ee - mm;            // s1 + s2
                    float num = fmaf(2.f, mu12, C1) * fmaf(2.f, s12, C2);
                    float den = (mm + C1) * (spp + C2);
                    local = fmaf(num, __builtin_amdgcn_rcpf(den), local);
                }
            }
        }
    }

    // ---------------- reduction: wave shuffle -> LDS -> double atomic ----------------
    #pragma unroll
    for (int off = 32; off > 0; off >>= 1) local += __shfl_down(local, off, 64);
    if ((t & 63) == 0) red[t >> 6] = local;
    __syncthreads();
    if (t == 0) {
        double s = (double)red[0] + (double)red[1] + (double)red[2] + (double)red[3];
        atomicAdd(acc, s);
    }
}

__global__ void ssim_fin(const double* __restrict__ acc, float* __restrict__ out)
{
    out[0] = (float)(acc[0] / TOTAL);
}

extern "C" void kernel_launch(void* const* d_in, const int* in_sizes, int n_in,
                              void* d_out, int out_size, void* d_ws, size_t ws_size,
                              hipStream_t stream)
{
    (void)in_sizes; (void)n_in; (void)out_size; (void)ws_size;
    const float* img1 = (const float*)d_in[0];
    const float* img2 = (const float*)d_in[1];
    double* acc = (double*)d_ws;

    hipMemsetAsync(d_ws, 0, sizeof(double), stream);
    dim3 grid((OUT_H + RPB - 1) / RPB, NIMG);   // 10 x 96 = 960 blocks
    hipLaunchKernelGGL(ssim_main, grid, dim3(256), 0, stream, img1, img2, acc);
    hipLaunchKernelGGL(ssim_fin, dim3(1), dim3(1), 0, stream, acc, (float*)d_out);
}